// Round 4
// baseline (125.947 us; speedup 1.0000x reference)
//
#include <hip/hip_runtime.h>
#include <math.h>

#define DIM     1024
#define NSTAGES 10
#define HALFD   512                   // angles per stage = DIM/2
#define TABN    (NSTAGES * HALFD)     // 5120 floats per table

// ---------------------------------------------------------------------------
// Prep: cos/sin tables into workspace. ws layout: cos[10][512] | sin[10][512]
// ---------------------------------------------------------------------------
__global__ void bf_prep(const float* __restrict__ ang, float* __restrict__ ws) {
    int i = blockIdx.x * blockDim.x + threadIdx.x;
    if (i < TABN) {
        float s, c;
        sincosf(ang[i], &s, &c);
        ws[i]        = c;
        ws[TABN + i] = s;
    }
}

// ---------------------------------------------------------------------------
// Stage-outer butterfly. Each wave holds FOUR rows in registers (v[r][c],
// 64 VGPRs) and walks the 10 stages once; per (stage, c-group) the C/S
// values are read from LDS ONCE and applied to all 4 rows. This is the
// register-friendly version of what the compiler tried (and failed) to do
// by hoisting in R3.
//
// Lane layout: lane owns elements e = 256*c + 4*lane + d.
//   stage 0,1  : intra-float4
//   stage 2..7 : cross-lane, shfl_xor mask m = 1<<(s-2)  (1..32)
//   stage 8,9  : intra-lane across c-groups
// Angle index for left element i at stage s: p = ((i>>(s+1))<<s) | (i&(half-1))
// ---------------------------------------------------------------------------
__global__ __launch_bounds__(256, 4) void bf_main(
    const float* __restrict__ x,
    const float* __restrict__ tab,
    float* __restrict__ out)
{
    __shared__ __align__(16) float cosT[TABN];
    __shared__ __align__(16) float sinT[TABN];
    const int tid  = threadIdx.x;
    const int lane = tid & 63;
    const int gwid = blockIdx.x * 4 + (tid >> 6);     // global wave id

    // ---- stage cos/sin tables into LDS (10 float4 loads/thread) ----------
    {
        const float4* s4 = (const float4*)tab;
        float4* c4 = (float4*)cosT;
        float4* n4 = (float4*)sinT;
        #pragma unroll
        for (int i = 0; i < TABN / 4 / 256; ++i) {    // 5 iterations
            const int idx = i * 256 + tid;
            c4[idx] = s4[idx];
            n4[idx] = s4[TABN / 4 + idx];
        }
    }

    // ---- load 4 rows into registers (issued before the barrier: in flight
    //      concurrently with the table staging) ---------------------------
    float4 v[4][4];
    const float4* xp = (const float4*)x + (size_t)gwid * 4 * (DIM / 4) + lane;
    #pragma unroll
    for (int r = 0; r < 4; ++r)
        #pragma unroll
        for (int c = 0; c < 4; ++c)
            v[r][c] = xp[r * 256 + c * 64];

    __syncthreads();

    // ---- stages 0,1: intra-float4. p = 128c + 2*lane + {0,1} -------------
    #pragma unroll
    for (int s01 = 0; s01 < 2; ++s01) {
        const float* cT = cosT + s01 * HALFD;
        const float* sT = sinT + s01 * HALFD;
        #pragma unroll
        for (int c = 0; c < 4; ++c) {
            const int p = 128 * c + 2 * lane;
            float2 cc = *(const float2*)&cT[p];
            float2 ss = *(const float2*)&sT[p];
            #pragma unroll
            for (int r = 0; r < 4; ++r) {
                float4 u = v[r][c];
                if (s01 == 0) {
                    v[r][c].x = cc.x * u.x + ss.x * u.y;
                    v[r][c].y = cc.x * u.y - ss.x * u.x;
                    v[r][c].z = cc.y * u.z + ss.y * u.w;
                    v[r][c].w = cc.y * u.w - ss.y * u.z;
                } else {
                    v[r][c].x = cc.x * u.x + ss.x * u.z;
                    v[r][c].z = cc.x * u.z - ss.x * u.x;
                    v[r][c].y = cc.y * u.y + ss.y * u.w;
                    v[r][c].w = cc.y * u.w - ss.y * u.y;
                }
            }
        }
    }

    // ---- stages 2..7: cross-lane via shfl_xor ----------------------------
    #pragma unroll
    for (int s = 2; s <= 7; ++s) {
        const int m = 1 << (s - 2);
        const float* cT = cosT + s * HALFD;
        const float* sT = sinT + s * HALFD;
        const int l0 = lane & ~m;                     // left lane of the pair
        const float sgn = (lane & m) ? -1.0f : 1.0f;
        #pragma unroll
        for (int c = 0; c < 4; ++c) {
            const int p0 = (((c << (7 - s)) + (l0 >> (s - 1))) << s)
                         + 4 * (l0 & (m - 1));
            float4 C = *(const float4*)&cT[p0];
            float4 S = *(const float4*)&sT[p0];
            S.x *= sgn; S.y *= sgn; S.z *= sgn; S.w *= sgn;
            #pragma unroll
            for (int r = 0; r < 4; ++r) {
                float4 u = v[r][c];
                float tx = __shfl_xor(u.x, m, 64);
                float ty = __shfl_xor(u.y, m, 64);
                float tz = __shfl_xor(u.z, m, 64);
                float tw = __shfl_xor(u.w, m, 64);
                v[r][c].x = C.x * u.x + S.x * tx;
                v[r][c].y = C.y * u.y + S.y * ty;
                v[r][c].z = C.z * u.z + S.z * tz;
                v[r][c].w = C.w * u.w + S.w * tw;
            }
        }
    }

    // ---- stage 8: pairs (c0,c1),(c2,c3); p = 256*g + 4*lane + d ----------
    {
        const float* cT = cosT + 8 * HALFD;
        const float* sT = sinT + 8 * HALFD;
        #pragma unroll
        for (int g = 0; g < 2; ++g) {
            const int p0 = 256 * g + 4 * lane;
            float4 C = *(const float4*)&cT[p0];
            float4 S = *(const float4*)&sT[p0];
            #pragma unroll
            for (int r = 0; r < 4; ++r) {
                float4 L = v[r][2 * g], Rr = v[r][2 * g + 1];
                v[r][2 * g].x     = C.x * L.x + S.x * Rr.x;
                v[r][2 * g].y     = C.y * L.y + S.y * Rr.y;
                v[r][2 * g].z     = C.z * L.z + S.z * Rr.z;
                v[r][2 * g].w     = C.w * L.w + S.w * Rr.w;
                v[r][2 * g + 1].x = C.x * Rr.x - S.x * L.x;
                v[r][2 * g + 1].y = C.y * Rr.y - S.y * L.y;
                v[r][2 * g + 1].z = C.z * Rr.z - S.z * L.z;
                v[r][2 * g + 1].w = C.w * Rr.w - S.w * L.w;
            }
        }
    }

    // ---- stage 9: pairs (c0,c2),(c1,c3) ----------------------------------
    {
        const float* cT = cosT + 9 * HALFD;
        const float* sT = sinT + 9 * HALFD;
        #pragma unroll
        for (int g = 0; g < 2; ++g) {
            const int p0 = 256 * g + 4 * lane;
            float4 C = *(const float4*)&cT[p0];
            float4 S = *(const float4*)&sT[p0];
            #pragma unroll
            for (int r = 0; r < 4; ++r) {
                float4 L = v[r][g], Rr = v[r][g + 2];
                v[r][g].x     = C.x * L.x + S.x * Rr.x;
                v[r][g].y     = C.y * L.y + S.y * Rr.y;
                v[r][g].z     = C.z * L.z + S.z * Rr.z;
                v[r][g].w     = C.w * L.w + S.w * Rr.w;
                v[r][g + 2].x = C.x * Rr.x - S.x * L.x;
                v[r][g + 2].y = C.y * Rr.y - S.y * L.y;
                v[r][g + 2].z = C.z * Rr.z - S.z * L.z;
                v[r][g + 2].w = C.w * Rr.w - S.w * L.w;
            }
        }
    }

    // ---- store 4 rows (plain stores: keep out L3-resident) ---------------
    float4* op = (float4*)out + (size_t)gwid * 4 * (DIM / 4) + lane;
    #pragma unroll
    for (int r = 0; r < 4; ++r)
        #pragma unroll
        for (int c = 0; c < 4; ++c)
            op[r * 256 + c * 64] = v[r][c];
}

extern "C" void kernel_launch(void* const* d_in, const int* in_sizes, int n_in,
                              void* d_out, int out_size, void* d_ws, size_t ws_size,
                              hipStream_t stream) {
    const float* x   = (const float*)d_in[0];
    const float* ang = (const float*)d_in[1];
    float* out = (float*)d_out;

    const int nrows = out_size / DIM;          // 16384
    // 4 waves/block x 4 rows/wave = 16 rows/block -> 1024 blocks
    const int nblocks = nrows / 16;

    float* tab = (float*)d_ws;                 // 40 KB, ws is plenty
    bf_prep<<<(TABN + 255) / 256, 256, 0, stream>>>(ang, tab);
    bf_main<<<nblocks, 256, 0, stream>>>(x, tab, out);
}

// Round 5
// 52.825 us; speedup vs baseline: 2.3842x; 2.3842x over previous
//
#include <hip/hip_runtime.h>
#include <math.h>

#define DIM     1024
#define NSTAGES 10
#define HALFD   512                   // angles per stage = DIM/2
#define TABN    (NSTAGES * HALFD)     // 5120 floats per table

// ---------------------------------------------------------------------------
// Prep: cos/sin tables into workspace. ws layout: cos[10][512] | sin[10][512]
// The table is tiny (40 KB) and read with wave-uniform/broadcast patterns by
// every wave -> L1/L2 resident. No LDS staging in the main kernel.
// ---------------------------------------------------------------------------
__global__ void bf_prep(const float* __restrict__ ang, float* __restrict__ ws) {
    int i = blockIdx.x * blockDim.x + threadIdx.x;
    if (i < TABN) {
        float s, c;
        sincosf(ang[i], &s, &c);
        ws[i]        = c;
        ws[TABN + i] = s;
    }
}

// ---------------------------------------------------------------------------
// Main butterfly. Lane owns elements e = 256*c + 4*lane + d of each row.
//   stage 0,1  : intra-float4
//   stage 2..7 : cross-lane, shfl_xor mask m = 1<<(s-2)  (1..32)
//   stage 8,9  : intra-lane across c-groups
// Angle index for left element i at stage s: p = ((i>>(s+1))<<s) | (i&(half-1))
//
// Each wave: 4 rows as 2 batches of 2. Batch loop is unroll(1) with a memory
// clobber so the compiler cannot hoist table loads across batches (the R3/R4
// register-explosion / spill failure mode). Table C/S values are loaded once
// per (stage, c-group) and applied to both rows (r-loop innermost).
// ---------------------------------------------------------------------------
__global__ __launch_bounds__(256) void bf_main(
    const float* __restrict__ x,
    const float* __restrict__ tab,
    float* __restrict__ out)
{
    const int tid  = threadIdx.x;
    const int lane = tid & 63;
    const int gwid = blockIdx.x * 4 + (tid >> 6);   // global wave id, 4 rows each

    const float* cosT = tab;
    const float* sinT = tab + TABN;

    const float4* xp = (const float4*)x   + (size_t)gwid * 4 * (DIM / 4) + lane;
    float4*       op = (float4*)      out + (size_t)gwid * 4 * (DIM / 4) + lane;

    #pragma unroll 1
    for (int b = 0; b < 2; ++b) {
        asm volatile("" ::: "memory");   // fence: no load hoisting across batches

        // ---- load 2 rows -------------------------------------------------
        float4 v[2][4];
        #pragma unroll
        for (int r = 0; r < 2; ++r)
            #pragma unroll
            for (int c = 0; c < 4; ++c)
                v[r][c] = xp[(2 * b + r) * 256 + c * 64];

        // ---- stages 0,1: intra-float4. p = 128c + 2*lane + {0,1} ---------
        #pragma unroll
        for (int s01 = 0; s01 < 2; ++s01) {
            const float* cT = cosT + s01 * HALFD;
            const float* sT = sinT + s01 * HALFD;
            #pragma unroll
            for (int c = 0; c < 4; ++c) {
                const int p = 128 * c + 2 * lane;
                float2 cc = *(const float2*)&cT[p];
                float2 ss = *(const float2*)&sT[p];
                #pragma unroll
                for (int r = 0; r < 2; ++r) {
                    float4 u = v[r][c];
                    if (s01 == 0) {
                        v[r][c].x = cc.x * u.x + ss.x * u.y;
                        v[r][c].y = cc.x * u.y - ss.x * u.x;
                        v[r][c].z = cc.y * u.z + ss.y * u.w;
                        v[r][c].w = cc.y * u.w - ss.y * u.z;
                    } else {
                        v[r][c].x = cc.x * u.x + ss.x * u.z;
                        v[r][c].z = cc.x * u.z - ss.x * u.x;
                        v[r][c].y = cc.y * u.y + ss.y * u.w;
                        v[r][c].w = cc.y * u.w - ss.y * u.y;
                    }
                }
            }
        }

        // ---- stages 2..7: cross-lane via shfl_xor ------------------------
        #pragma unroll
        for (int s = 2; s <= 7; ++s) {
            const int m = 1 << (s - 2);
            const float* cT = cosT + s * HALFD;
            const float* sT = sinT + s * HALFD;
            const int l0 = lane & ~m;               // left lane of the pair
            const float sgn = (lane & m) ? -1.0f : 1.0f;
            #pragma unroll
            for (int c = 0; c < 4; ++c) {
                const int p0 = (((c << (7 - s)) + (l0 >> (s - 1))) << s)
                             + 4 * (l0 & (m - 1));
                float4 C = *(const float4*)&cT[p0];
                float4 S = *(const float4*)&sT[p0];
                S.x *= sgn; S.y *= sgn; S.z *= sgn; S.w *= sgn;
                #pragma unroll
                for (int r = 0; r < 2; ++r) {
                    float4 u = v[r][c];
                    float tx = __shfl_xor(u.x, m, 64);
                    float ty = __shfl_xor(u.y, m, 64);
                    float tz = __shfl_xor(u.z, m, 64);
                    float tw = __shfl_xor(u.w, m, 64);
                    v[r][c].x = C.x * u.x + S.x * tx;
                    v[r][c].y = C.y * u.y + S.y * ty;
                    v[r][c].z = C.z * u.z + S.z * tz;
                    v[r][c].w = C.w * u.w + S.w * tw;
                }
            }
        }

        // ---- stage 8: pairs (c0,c1),(c2,c3); p = 256*g + 4*lane + d ------
        {
            const float* cT = cosT + 8 * HALFD;
            const float* sT = sinT + 8 * HALFD;
            #pragma unroll
            for (int g = 0; g < 2; ++g) {
                const int p0 = 256 * g + 4 * lane;
                float4 C = *(const float4*)&cT[p0];
                float4 S = *(const float4*)&sT[p0];
                #pragma unroll
                for (int r = 0; r < 2; ++r) {
                    float4 L = v[r][2 * g], Rr = v[r][2 * g + 1];
                    v[r][2 * g].x     = C.x * L.x + S.x * Rr.x;
                    v[r][2 * g].y     = C.y * L.y + S.y * Rr.y;
                    v[r][2 * g].z     = C.z * L.z + S.z * Rr.z;
                    v[r][2 * g].w     = C.w * L.w + S.w * Rr.w;
                    v[r][2 * g + 1].x = C.x * Rr.x - S.x * L.x;
                    v[r][2 * g + 1].y = C.y * Rr.y - S.y * L.y;
                    v[r][2 * g + 1].z = C.z * Rr.z - S.z * L.z;
                    v[r][2 * g + 1].w = C.w * Rr.w - S.w * L.w;
                }
            }
        }

        // ---- stage 9: pairs (c0,c2),(c1,c3) ------------------------------
        {
            const float* cT = cosT + 9 * HALFD;
            const float* sT = sinT + 9 * HALFD;
            #pragma unroll
            for (int g = 0; g < 2; ++g) {
                const int p0 = 256 * g + 4 * lane;
                float4 C = *(const float4*)&cT[p0];
                float4 S = *(const float4*)&sT[p0];
                #pragma unroll
                for (int r = 0; r < 2; ++r) {
                    float4 L = v[r][g], Rr = v[r][g + 2];
                    v[r][g].x     = C.x * L.x + S.x * Rr.x;
                    v[r][g].y     = C.y * L.y + S.y * Rr.y;
                    v[r][g].z     = C.z * L.z + S.z * Rr.z;
                    v[r][g].w     = C.w * L.w + S.w * Rr.w;
                    v[r][g + 2].x = C.x * Rr.x - S.x * L.x;
                    v[r][g + 2].y = C.y * Rr.y - S.y * L.y;
                    v[r][g + 2].z = C.z * Rr.z - S.z * L.z;
                    v[r][g + 2].w = C.w * Rr.w - S.w * L.w;
                }
            }
        }

        // ---- store 2 rows ------------------------------------------------
        #pragma unroll
        for (int r = 0; r < 2; ++r)
            #pragma unroll
            for (int c = 0; c < 4; ++c)
                op[(2 * b + r) * 256 + c * 64] = v[r][c];
    }
}

extern "C" void kernel_launch(void* const* d_in, const int* in_sizes, int n_in,
                              void* d_out, int out_size, void* d_ws, size_t ws_size,
                              hipStream_t stream) {
    const float* x   = (const float*)d_in[0];
    const float* ang = (const float*)d_in[1];
    float* out = (float*)d_out;

    const int nrows = out_size / DIM;          // 16384
    // 4 waves/block x 4 rows/wave = 16 rows/block -> 1024 blocks,
    // all resident in one dispatch round (16 waves/CU at ~108 VGPRs).
    const int nblocks = nrows / 16;

    float* tab = (float*)d_ws;                 // 40 KB
    bf_prep<<<(TABN + 255) / 256, 256, 0, stream>>>(ang, tab);
    bf_main<<<nblocks, 256, 0, stream>>>(x, tab, out);
}